// Round 3
// baseline (128.182 us; speedup 1.0000x reference)
//
#include <hip/hip_runtime.h>

// ROI max-pooling, faithful to the reference (including the buggy min/max
// ordering). feat: [B=4, C=64, H=128, W=128] f32; boxes: [B, N=64, 7] f32
// out: [B, N, C, 7, 7] f32
//
// Round-3: wave = (box, channel); lane = x-offset in ROI. Flat y-loop with a
// manual 4-deep load pipeline (independent clamp-guarded loads) to kill the
// serial L3-latency chain seen in round 2 (VGPR=12, VALUBusy 9%). Box coords
// readfirstlane'd so bin-membership checks compile to scalar branches.
// 128-thread blocks (2 waves) for fine-grained tail balancing: 8192 blocks.

constexpr int Bb = 4, Cc = 64, Hh = 128, Ww = 128, Nn = 64, BOX_DIM = 7;
constexpr int POOL = 7;
constexpr int WAVES = 2;            // channels per block
constexpr int PITCH = Ww + 1;       // 129: breaks power-of-2 bank stride

__global__ __launch_bounds__(128) void roi_pool_kernel(
    const float* __restrict__ feat,
    const float* __restrict__ boxes,
    float* __restrict__ out)
{
    __shared__ float colmax[WAVES][POOL][PITCH];   // 7224 B

    const int bn   = blockIdx.x;                   // box index (B*N)
    const int b    = bn >> 6;                      // Nn = 64
    const int wave = threadIdx.x >> 6;
    const int lane = threadIdx.x & 63;
    const int c    = blockIdx.y * WAVES + wave;

    // --- box decode (same address for all lanes -> broadcast load) ---
    const float* bx = boxes + (size_t)bn * BOX_DIM;
    bool valid = false;
#pragma unroll
    for (int i = 0; i < BOX_DIM; ++i) valid = valid || (bx[i] != 0.0f);

    float x1 = fminf(fmaxf(bx[0], 0.0f), (float)(Ww - 1));
    float y1 = fminf(fmaxf(bx[1], 0.0f), (float)(Hh - 1));
    float x2 = fminf(fmaxf(bx[2], 0.0f), (float)(Ww - 1));
    float y2 = fminf(fmaxf(bx[3], 0.0f), (float)(Hh - 1));
    // reference ordering exactly (sequential updates)
    x1 = fminf(x1, x2);
    x2 = fmaxf(x1, x2);
    y1 = fminf(y1, y2);
    y2 = fmaxf(y1, y2);

    // make coords provably wave-uniform -> scalar branches below
    int x1i = __builtin_amdgcn_readfirstlane((int)x1);
    int x2i = __builtin_amdgcn_readfirstlane((int)x2);
    int y1i = __builtin_amdgcn_readfirstlane((int)y1);
    int y2i = __builtin_amdgcn_readfirstlane((int)y2);
    if (x2i == x1i) x2i = x1i + 1;
    if (y2i == y1i) y2i = y1i + 1;
    const int Lh = y2i - y1i;      // 1..127
    const int Lw = x2i - x1i;      // 1..127

    // y-bin bounds (uniform); e[p] <= y2i always
    int s[POOL], e[POOL];
#pragma unroll
    for (int p = 0; p < POOL; ++p) {
        s[p] = y1i + (p * Lh) / POOL;
        e[p] = y1i + ((p + 1) * Lh + POOL - 1) / POOL;
    }

    const float* fp = feat + ((size_t)(b * Cc + c) * Hh) * Ww;

    // --- stage 1: per-lane column maxes, 4-deep pipelined flat y-loop ---
    for (int x0 = 0; x0 < Lw; x0 += 64) {
        const int xoff = x0 + lane;
        if (xoff < Lw) {
            const float* col = fp + (x1i + xoff);
            float pm[POOL];
#pragma unroll
            for (int p = 0; p < POOL; ++p) pm[p] = -INFINITY;

            const int ylast = y2i - 1;
            int y = y1i;
            // prologue: 4 independent loads in flight (clamped -> always valid)
            float v0 = col[(size_t)min(y + 0, ylast) * Ww];
            float v1 = col[(size_t)min(y + 1, ylast) * Ww];
            float v2 = col[(size_t)min(y + 2, ylast) * Ww];
            float v3 = col[(size_t)min(y + 3, ylast) * Ww];
            while (y < y2i) {
                const float w0 = v0, w1 = v1, w2 = v2, w3 = v3;
                // issue next 4 before consuming current 4
                v0 = col[(size_t)min(y + 4, ylast) * Ww];
                v1 = col[(size_t)min(y + 5, ylast) * Ww];
                v2 = col[(size_t)min(y + 6, ylast) * Ww];
                v3 = col[(size_t)min(y + 7, ylast) * Ww];
#pragma unroll
                for (int p = 0; p < POOL; ++p) {
                    // uniform scalar conditions; e[p] <= y2i so no extra tail check
                    if (y + 0 >= s[p] && y + 0 < e[p]) pm[p] = fmaxf(pm[p], w0);
                    if (y + 1 >= s[p] && y + 1 < e[p]) pm[p] = fmaxf(pm[p], w1);
                    if (y + 2 >= s[p] && y + 2 < e[p]) pm[p] = fmaxf(pm[p], w2);
                    if (y + 3 >= s[p] && y + 3 < e[p]) pm[p] = fmaxf(pm[p], w3);
                }
                y += 4;
            }
#pragma unroll
            for (int p = 0; p < POOL; ++p) colmax[wave][p][xoff] = pm[p];
        }
    }

    __syncthreads();

    // --- stage 2: 49 lanes reduce x-bins from LDS, write 49 outputs ---
    if (lane < POOL * POOL) {
        const int p = lane / POOL;
        const int q = lane % POOL;
        const int xs = (q * Lw) / POOL;
        const int xe = ((q + 1) * Lw + POOL - 1) / POOL;
        float m = -INFINITY;
        for (int xo = xs; xo < xe; ++xo)
            m = fmaxf(m, colmax[wave][p][xo]);
        if (!valid) m = 0.0f;
        out[((size_t)bn * Cc + c) * (POOL * POOL) + lane] = m;
    }
}

extern "C" void kernel_launch(void* const* d_in, const int* in_sizes, int n_in,
                              void* d_out, int out_size, void* d_ws, size_t ws_size,
                              hipStream_t stream) {
    const float* feat  = (const float*)d_in[0];
    const float* boxes = (const float*)d_in[1];
    float* out = (float*)d_out;

    dim3 grid(Bb * Nn, Cc / WAVES);   // 256 x 32 = 8192 blocks, 2 waves each
    roi_pool_kernel<<<grid, 128, 0, stream>>>(feat, boxes, out);
}

// Round 4
// 37.319 us; speedup vs baseline: 3.4348x; 3.4348x over previous
//
#include <hip/hip_runtime.h>

// ROI max-pooling, faithful to the reference (including the buggy min/max
// ordering). feat: [B=4, C=64, H=128, W=128] f32; boxes: [B, N=64, 7] f32
// out: [B, N, C, 7, 7] f32
//
// Round-4: wave = (box, channel); lane = x-offset. LOOP INTERCHANGE over the
// 7 y-bins: step k loads row s[p]+k for every bin p (7 independent loads,
// separate accumulators, row clamped to e[p]-1 so no branches — redundant
// fmax of the last row is idempotent). Hand-pipelined 1 k-step ahead -> 14
// loads in flight. All bounds wave-uniform (readfirstlane) -> scalar control.

constexpr int Bb = 4, Cc = 64, Hh = 128, Ww = 128, Nn = 64, BOX_DIM = 7;
constexpr int POOL = 7;
constexpr int WAVES = 2;            // channels per block
constexpr int PITCH = Ww + 1;       // 129: breaks power-of-2 bank stride

__global__ __launch_bounds__(128) void roi_pool_kernel(
    const float* __restrict__ feat,
    const float* __restrict__ boxes,
    float* __restrict__ out)
{
    __shared__ float colmax[WAVES][POOL][PITCH];   // 7224 B

    const int bn   = blockIdx.x;                   // box index (B*N)
    const int b    = bn >> 6;                      // Nn = 64
    const int wave = threadIdx.x >> 6;
    const int lane = threadIdx.x & 63;
    const int c    = blockIdx.y * WAVES + wave;

    // --- box decode (same address for all lanes -> broadcast load) ---
    const float* bx = boxes + (size_t)bn * BOX_DIM;
    bool valid = false;
#pragma unroll
    for (int i = 0; i < BOX_DIM; ++i) valid = valid || (bx[i] != 0.0f);

    float x1 = fminf(fmaxf(bx[0], 0.0f), (float)(Ww - 1));
    float y1 = fminf(fmaxf(bx[1], 0.0f), (float)(Hh - 1));
    float x2 = fminf(fmaxf(bx[2], 0.0f), (float)(Ww - 1));
    float y2 = fminf(fmaxf(bx[3], 0.0f), (float)(Hh - 1));
    // reference ordering exactly (sequential updates)
    x1 = fminf(x1, x2);
    x2 = fmaxf(x1, x2);
    y1 = fminf(y1, y2);
    y2 = fmaxf(y1, y2);

    // wave-uniform ints -> scalar control flow everywhere below
    int x1i = __builtin_amdgcn_readfirstlane((int)x1);
    int x2i = __builtin_amdgcn_readfirstlane((int)x2);
    int y1i = __builtin_amdgcn_readfirstlane((int)y1);
    int y2i = __builtin_amdgcn_readfirstlane((int)y2);
    if (x2i == x1i) x2i = x1i + 1;
    if (y2i == y1i) y2i = y1i + 1;
    const int Lh = y2i - y1i;      // 1..127
    const int Lw = x2i - x1i;      // 1..127

    // y-bin bounds (uniform); bin lengths differ by <=1; all >=1
    int s_[POOL], e_[POOL];
    int kmax = 0;
#pragma unroll
    for (int p = 0; p < POOL; ++p) {
        s_[p] = y1i + (p * Lh) / POOL;
        e_[p] = y1i + ((p + 1) * Lh + POOL - 1) / POOL;
        kmax = max(kmax, e_[p] - s_[p]);
    }

    const float* fp = feat + ((size_t)(b * Cc + c) * Hh) * Ww;

    // --- stage 1: per-lane column maxes; 7 independent chains, 14 loads in flight
    for (int x0 = 0; x0 < Lw; x0 += 64) {
        const int xoff = x0 + lane;
        if (x0 >= Lw) break;
        const bool active = xoff < Lw;
        const int xcol = x1i + min(xoff, Lw - 1);   // clamp keeps loads in-bounds

        float pm[POOL], vv[POOL];
#pragma unroll
        for (int p = 0; p < POOL; ++p) {
            pm[p] = -INFINITY;
            vv[p] = fp[(size_t)(s_[p] * Ww) + xcol];     // k = 0
        }
        for (int k = 1; k <= kmax; ++k) {
            float w[POOL];
#pragma unroll
            for (int p = 0; p < POOL; ++p) w[p] = vv[p];
            // prefetch step k (row clamped to bin end; redundant re-max is fine)
#pragma unroll
            for (int p = 0; p < POOL; ++p) {
                const int row = min(s_[p] + k, e_[p] - 1);   // uniform scalar
                vv[p] = fp[(size_t)(row * Ww) + xcol];
            }
#pragma unroll
            for (int p = 0; p < POOL; ++p) pm[p] = fmaxf(pm[p], w[p]);
        }

        if (active) {
#pragma unroll
            for (int p = 0; p < POOL; ++p) colmax[wave][p][xoff] = pm[p];
        }
    }

    __syncthreads();

    // --- stage 2: 49 lanes reduce x-bins from LDS, write 49 outputs ---
    if (lane < POOL * POOL) {
        const int p = lane / POOL;
        const int q = lane % POOL;
        const int xs = (q * Lw) / POOL;
        const int xe = ((q + 1) * Lw + POOL - 1) / POOL;
        float m = -INFINITY;
        for (int xo = xs; xo < xe; ++xo)
            m = fmaxf(m, colmax[wave][p][xo]);
        if (!valid) m = 0.0f;
        out[((size_t)bn * Cc + c) * (POOL * POOL) + lane] = m;
    }
}

extern "C" void kernel_launch(void* const* d_in, const int* in_sizes, int n_in,
                              void* d_out, int out_size, void* d_ws, size_t ws_size,
                              hipStream_t stream) {
    const float* feat  = (const float*)d_in[0];
    const float* boxes = (const float*)d_in[1];
    float* out = (float*)d_out;

    dim3 grid(Bb * Nn, Cc / WAVES);   // 256 x 32 = 8192 blocks, 2 waves each
    roi_pool_kernel<<<grid, 128, 0, stream>>>(feat, boxes, out);
}

// Round 5
// 32.349 us; speedup vs baseline: 3.9625x; 1.1536x over previous
//
#include <hip/hip_runtime.h>

// ROI max-pooling, faithful to the reference (including the buggy min/max
// ordering). feat: [B=4, C=64, H=128, W=128] f32; boxes: [B, N=64, 7] f32
// out: [B, N, C, 7, 7] f32
//
// Round-5: wave = (box, channel); lane = x-offset. Loop interchange over the
// 7 y-bins (round 4) PLUS a 4-bank software pipeline: banks A..D hold rows
// k..k+3 for all 7 bins -> up to 28 loads in flight; each bank is consumed a
// full iteration (~4 rows of issue+VALU) after it was issued, covering L2/L3
// latency. Row indices are wave-uniform scalars clamped to the bin end, so
// overshoot iterations are idempotent re-maxes (no tail branches).

constexpr int Bb = 4, Cc = 64, Hh = 128, Ww = 128, Nn = 64, BOX_DIM = 7;
constexpr int POOL = 7;
constexpr int WAVES = 2;            // channels per block
constexpr int PITCH = Ww + 1;       // 129: breaks power-of-2 bank stride

__global__ __launch_bounds__(128) void roi_pool_kernel(
    const float* __restrict__ feat,
    const float* __restrict__ boxes,
    float* __restrict__ out)
{
    __shared__ float colmax[WAVES][POOL][PITCH];   // 7224 B

    const int bn   = blockIdx.x;                   // box index (B*N)
    const int b    = bn >> 6;                      // Nn = 64
    const int wave = threadIdx.x >> 6;
    const int lane = threadIdx.x & 63;
    const int c    = blockIdx.y * WAVES + wave;

    // --- box decode (same address for all lanes -> broadcast load) ---
    const float* bx = boxes + (size_t)bn * BOX_DIM;
    bool valid = false;
#pragma unroll
    for (int i = 0; i < BOX_DIM; ++i) valid = valid || (bx[i] != 0.0f);

    float x1 = fminf(fmaxf(bx[0], 0.0f), (float)(Ww - 1));
    float y1 = fminf(fmaxf(bx[1], 0.0f), (float)(Hh - 1));
    float x2 = fminf(fmaxf(bx[2], 0.0f), (float)(Ww - 1));
    float y2 = fminf(fmaxf(bx[3], 0.0f), (float)(Hh - 1));
    // reference ordering exactly (sequential updates)
    x1 = fminf(x1, x2);
    x2 = fmaxf(x1, x2);
    y1 = fminf(y1, y2);
    y2 = fmaxf(y1, y2);

    // wave-uniform ints -> scalar control flow everywhere below
    int x1i = __builtin_amdgcn_readfirstlane((int)x1);
    int x2i = __builtin_amdgcn_readfirstlane((int)x2);
    int y1i = __builtin_amdgcn_readfirstlane((int)y1);
    int y2i = __builtin_amdgcn_readfirstlane((int)y2);
    if (x2i == x1i) x2i = x1i + 1;
    if (y2i == y1i) y2i = y1i + 1;
    const int Lh = y2i - y1i;      // 1..127
    const int Lw = x2i - x1i;      // 1..127

    // y-bin bounds (uniform); bin lengths differ by <=1; all >=1
    int s_[POOL], el_[POOL];       // el_ = e[p]-1 (last row of bin)
    int kmax = 0;
#pragma unroll
    for (int p = 0; p < POOL; ++p) {
        s_[p] = y1i + (p * Lh) / POOL;
        const int e = y1i + ((p + 1) * Lh + POOL - 1) / POOL;
        el_[p] = e - 1;
        kmax = max(kmax, e - s_[p]);
    }

    const float* fp = feat + ((size_t)(b * Cc + c) * Hh) * Ww;

    // --- stage 1: per-lane column maxes; 4-bank pipeline, 28 loads in flight
    for (int x0 = 0; x0 < Lw; x0 += 64) {
        const int xoff = x0 + lane;
        const bool active = xoff < Lw;
        const int xcol = x1i + min(xoff, Lw - 1);   // clamp keeps loads in-bounds

        float pm[POOL], fA[POOL], fB[POOL], fC[POOL], fD[POOL];
#pragma unroll
        for (int p = 0; p < POOL; ++p) {
            pm[p] = -INFINITY;
            fA[p] = fp[(size_t)(min(s_[p] + 0, el_[p]) * Ww) + xcol];
            fB[p] = fp[(size_t)(min(s_[p] + 1, el_[p]) * Ww) + xcol];
            fC[p] = fp[(size_t)(min(s_[p] + 2, el_[p]) * Ww) + xcol];
            fD[p] = fp[(size_t)(min(s_[p] + 3, el_[p]) * Ww) + xcol];
        }

        const int kiter = (kmax + 3) >> 2;   // overshoot is idempotent
        for (int k = 0; k < kiter; ++k) {
            const int kk = k * 4;
            float w[POOL];
#pragma unroll
            for (int p = 0; p < POOL; ++p) w[p] = fA[p];
#pragma unroll
            for (int p = 0; p < POOL; ++p)
                fA[p] = fp[(size_t)(min(s_[p] + kk + 4, el_[p]) * Ww) + xcol];
#pragma unroll
            for (int p = 0; p < POOL; ++p) pm[p] = fmaxf(pm[p], w[p]);

#pragma unroll
            for (int p = 0; p < POOL; ++p) w[p] = fB[p];
#pragma unroll
            for (int p = 0; p < POOL; ++p)
                fB[p] = fp[(size_t)(min(s_[p] + kk + 5, el_[p]) * Ww) + xcol];
#pragma unroll
            for (int p = 0; p < POOL; ++p) pm[p] = fmaxf(pm[p], w[p]);

#pragma unroll
            for (int p = 0; p < POOL; ++p) w[p] = fC[p];
#pragma unroll
            for (int p = 0; p < POOL; ++p)
                fC[p] = fp[(size_t)(min(s_[p] + kk + 6, el_[p]) * Ww) + xcol];
#pragma unroll
            for (int p = 0; p < POOL; ++p) pm[p] = fmaxf(pm[p], w[p]);

#pragma unroll
            for (int p = 0; p < POOL; ++p) w[p] = fD[p];
#pragma unroll
            for (int p = 0; p < POOL; ++p)
                fD[p] = fp[(size_t)(min(s_[p] + kk + 7, el_[p]) * Ww) + xcol];
#pragma unroll
            for (int p = 0; p < POOL; ++p) pm[p] = fmaxf(pm[p], w[p]);
        }

        if (active) {
#pragma unroll
            for (int p = 0; p < POOL; ++p) colmax[wave][p][xoff] = pm[p];
        }
    }

    __syncthreads();

    // --- stage 2: 49 lanes reduce x-bins from LDS, write 49 outputs ---
    if (lane < POOL * POOL) {
        const int p = lane / POOL;
        const int q = lane % POOL;
        const int xs = (q * Lw) / POOL;
        const int xe = ((q + 1) * Lw + POOL - 1) / POOL;
        float m = -INFINITY;
        for (int xo = xs; xo < xe; ++xo)
            m = fmaxf(m, colmax[wave][p][xo]);
        if (!valid) m = 0.0f;
        out[((size_t)bn * Cc + c) * (POOL * POOL) + lane] = m;
    }
}

extern "C" void kernel_launch(void* const* d_in, const int* in_sizes, int n_in,
                              void* d_out, int out_size, void* d_ws, size_t ws_size,
                              hipStream_t stream) {
    const float* feat  = (const float*)d_in[0];
    const float* boxes = (const float*)d_in[1];
    float* out = (float*)d_out;

    dim3 grid(Bb * Nn, Cc / WAVES);   // 256 x 32 = 8192 blocks, 2 waves each
    roi_pool_kernel<<<grid, 128, 0, stream>>>(feat, boxes, out);
}

// Round 6
// 25.263 us; speedup vs baseline: 5.0738x; 1.2805x over previous
//
#include <hip/hip_runtime.h>

// ROI max-pooling, faithful to the reference (including the buggy min/max
// ordering). feat: [B=4, C=64, H=128, W=128] f32; boxes: [B, N=64, 7] f32
// out: [B, N, C, 7, 7] f32
//
// Round-6: same 4-bank interchanged pipeline as round 5, but the GRID DIMS
// ARE SWAPPED so blockIdx.x = channel-group. Workgroup->XCD assignment is
// round-robin on the linearized block id (x fastest), so XCD = cgroup % 8:
// each XCD touches only 8 of 64 channel planes = 2 MB of feat, which is
// L2-resident (4 MB/XCD). Round-5 layout put box%8 on the XCD -> each XCD
// streamed ~16 MB through Infinity Cache every call (L3-BW bound, ~32 us).

constexpr int Bb = 4, Cc = 64, Hh = 128, Ww = 128, Nn = 64, BOX_DIM = 7;
constexpr int POOL = 7;
constexpr int WAVES = 2;            // channels per block
constexpr int PITCH = Ww + 1;       // 129: breaks power-of-2 bank stride

__global__ __launch_bounds__(128) void roi_pool_kernel(
    const float* __restrict__ feat,
    const float* __restrict__ boxes,
    float* __restrict__ out)
{
    __shared__ float colmax[WAVES][POOL][PITCH];   // 7224 B

    const int bn   = blockIdx.y;                   // box index (B*N)
    const int b    = bn >> 6;                      // Nn = 64
    const int wave = threadIdx.x >> 6;
    const int lane = threadIdx.x & 63;
    const int c    = blockIdx.x * WAVES + wave;    // channel (x-dim -> XCD slice)

    // --- box decode (same address for all lanes -> broadcast load) ---
    const float* bx = boxes + (size_t)bn * BOX_DIM;
    bool valid = false;
#pragma unroll
    for (int i = 0; i < BOX_DIM; ++i) valid = valid || (bx[i] != 0.0f);

    float x1 = fminf(fmaxf(bx[0], 0.0f), (float)(Ww - 1));
    float y1 = fminf(fmaxf(bx[1], 0.0f), (float)(Hh - 1));
    float x2 = fminf(fmaxf(bx[2], 0.0f), (float)(Ww - 1));
    float y2 = fminf(fmaxf(bx[3], 0.0f), (float)(Hh - 1));
    // reference ordering exactly (sequential updates)
    x1 = fminf(x1, x2);
    x2 = fmaxf(x1, x2);
    y1 = fminf(y1, y2);
    y2 = fmaxf(y1, y2);

    // wave-uniform ints -> scalar control flow everywhere below
    int x1i = __builtin_amdgcn_readfirstlane((int)x1);
    int x2i = __builtin_amdgcn_readfirstlane((int)x2);
    int y1i = __builtin_amdgcn_readfirstlane((int)y1);
    int y2i = __builtin_amdgcn_readfirstlane((int)y2);
    if (x2i == x1i) x2i = x1i + 1;
    if (y2i == y1i) y2i = y1i + 1;
    const int Lh = y2i - y1i;      // 1..127
    const int Lw = x2i - x1i;      // 1..127

    // y-bin bounds (uniform); bin lengths differ by <=1; all >=1
    int s_[POOL], el_[POOL];       // el_ = e[p]-1 (last row of bin)
    int kmax = 0;
#pragma unroll
    for (int p = 0; p < POOL; ++p) {
        s_[p] = y1i + (p * Lh) / POOL;
        const int e = y1i + ((p + 1) * Lh + POOL - 1) / POOL;
        el_[p] = e - 1;
        kmax = max(kmax, e - s_[p]);
    }

    const float* fp = feat + ((size_t)(b * Cc + c) * Hh) * Ww;

    // --- stage 1: per-lane column maxes; 4-bank pipeline, 28 loads in flight
    for (int x0 = 0; x0 < Lw; x0 += 64) {
        const int xoff = x0 + lane;
        const bool active = xoff < Lw;
        const int xcol = x1i + min(xoff, Lw - 1);   // clamp keeps loads in-bounds

        float pm[POOL], fA[POOL], fB[POOL], fC[POOL], fD[POOL];
#pragma unroll
        for (int p = 0; p < POOL; ++p) {
            pm[p] = -INFINITY;
            fA[p] = fp[(size_t)(min(s_[p] + 0, el_[p]) * Ww) + xcol];
            fB[p] = fp[(size_t)(min(s_[p] + 1, el_[p]) * Ww) + xcol];
            fC[p] = fp[(size_t)(min(s_[p] + 2, el_[p]) * Ww) + xcol];
            fD[p] = fp[(size_t)(min(s_[p] + 3, el_[p]) * Ww) + xcol];
        }

        const int kiter = (kmax + 3) >> 2;   // overshoot is idempotent
        for (int k = 0; k < kiter; ++k) {
            const int kk = k * 4;
            float w[POOL];
#pragma unroll
            for (int p = 0; p < POOL; ++p) w[p] = fA[p];
#pragma unroll
            for (int p = 0; p < POOL; ++p)
                fA[p] = fp[(size_t)(min(s_[p] + kk + 4, el_[p]) * Ww) + xcol];
#pragma unroll
            for (int p = 0; p < POOL; ++p) pm[p] = fmaxf(pm[p], w[p]);

#pragma unroll
            for (int p = 0; p < POOL; ++p) w[p] = fB[p];
#pragma unroll
            for (int p = 0; p < POOL; ++p)
                fB[p] = fp[(size_t)(min(s_[p] + kk + 5, el_[p]) * Ww) + xcol];
#pragma unroll
            for (int p = 0; p < POOL; ++p) pm[p] = fmaxf(pm[p], w[p]);

#pragma unroll
            for (int p = 0; p < POOL; ++p) w[p] = fC[p];
#pragma unroll
            for (int p = 0; p < POOL; ++p)
                fC[p] = fp[(size_t)(min(s_[p] + kk + 6, el_[p]) * Ww) + xcol];
#pragma unroll
            for (int p = 0; p < POOL; ++p) pm[p] = fmaxf(pm[p], w[p]);

#pragma unroll
            for (int p = 0; p < POOL; ++p) w[p] = fD[p];
#pragma unroll
            for (int p = 0; p < POOL; ++p)
                fD[p] = fp[(size_t)(min(s_[p] + kk + 7, el_[p]) * Ww) + xcol];
#pragma unroll
            for (int p = 0; p < POOL; ++p) pm[p] = fmaxf(pm[p], w[p]);
        }

        if (active) {
#pragma unroll
            for (int p = 0; p < POOL; ++p) colmax[wave][p][xoff] = pm[p];
        }
    }

    __syncthreads();

    // --- stage 2: 49 lanes reduce x-bins from LDS, write 49 outputs ---
    if (lane < POOL * POOL) {
        const int p = lane / POOL;
        const int q = lane % POOL;
        const int xs = (q * Lw) / POOL;
        const int xe = ((q + 1) * Lw + POOL - 1) / POOL;
        float m = -INFINITY;
        for (int xo = xs; xo < xe; ++xo)
            m = fmaxf(m, colmax[wave][p][xo]);
        if (!valid) m = 0.0f;
        out[((size_t)bn * Cc + c) * (POOL * POOL) + lane] = m;
    }
}

extern "C" void kernel_launch(void* const* d_in, const int* in_sizes, int n_in,
                              void* d_out, int out_size, void* d_ws, size_t ws_size,
                              hipStream_t stream) {
    const float* feat  = (const float*)d_in[0];
    const float* boxes = (const float*)d_in[1];
    float* out = (float*)d_out;

    // x = channel-group (fast dim -> XCD round-robin), y = box
    dim3 grid(Cc / WAVES, Bb * Nn);   // 32 x 256 = 8192 blocks, 2 waves each
    roi_pool_kernel<<<grid, 128, 0, stream>>>(feat, boxes, out);
}

// Round 7
// 24.739 us; speedup vs baseline: 5.1815x; 1.0212x over previous
//
#include <hip/hip_runtime.h>

// ROI max-pooling, faithful to the reference (including the buggy min/max
// ordering). feat: [B=4, C=64, H=128, W=128] f32; boxes: [B, N=64, 7] f32
// out: [B, N, C, 7, 7] f32
//
// Round-7: exact-trip flat row walk. Each ROI row is loaded exactly once
// (vs ~1.9x redundancy of the round-5/6 banked pipeline). buf[8] ring
// (fully unrolled -> registers) keeps 8 loads in flight. Bin segmentation is
// a scalar state machine: while (y >= e_cur) flush cur->LDS, advance bin,
// seed 1-row overlap (s_new == y-1 -> cur = prev). Overshoot rows consume
// the clamped last row idempotently; trailing bins filled from prev.
// Grid keeps blockIdx.x = channel-group (XCD L2 slice residency, round 6).

constexpr int Bb = 4, Cc = 64, Hh = 128, Ww = 128, Nn = 64, BOX_DIM = 7;
constexpr int POOL = 7;
constexpr int WAVES = 2;            // channels per block
constexpr int PITCH = Ww + 1;       // 129: breaks power-of-2 bank stride

__global__ __launch_bounds__(128) void roi_pool_kernel(
    const float* __restrict__ feat,
    const float* __restrict__ boxes,
    float* __restrict__ out)
{
    __shared__ float colmax[WAVES][POOL][PITCH];   // 7224 B

    const int bn   = blockIdx.y;                   // box index (B*N)
    const int b    = bn >> 6;                      // Nn = 64
    const int wave = threadIdx.x >> 6;
    const int lane = threadIdx.x & 63;
    const int c    = blockIdx.x * WAVES + wave;    // channel (x-dim -> XCD slice)

    // --- box decode (same address for all lanes -> broadcast load) ---
    const float* bx = boxes + (size_t)bn * BOX_DIM;
    bool valid = false;
#pragma unroll
    for (int i = 0; i < BOX_DIM; ++i) valid = valid || (bx[i] != 0.0f);

    float x1 = fminf(fmaxf(bx[0], 0.0f), (float)(Ww - 1));
    float y1 = fminf(fmaxf(bx[1], 0.0f), (float)(Hh - 1));
    float x2 = fminf(fmaxf(bx[2], 0.0f), (float)(Ww - 1));
    float y2 = fminf(fmaxf(bx[3], 0.0f), (float)(Hh - 1));
    // reference ordering exactly (sequential updates)
    x1 = fminf(x1, x2);
    x2 = fmaxf(x1, x2);
    y1 = fminf(y1, y2);
    y2 = fmaxf(y1, y2);

    // wave-uniform ints -> scalar control flow everywhere below
    int x1i = __builtin_amdgcn_readfirstlane((int)x1);
    int x2i = __builtin_amdgcn_readfirstlane((int)x2);
    int y1i = __builtin_amdgcn_readfirstlane((int)y1);
    int y2i = __builtin_amdgcn_readfirstlane((int)y2);
    if (x2i == x1i) x2i = x1i + 1;
    if (y2i == y1i) y2i = y1i + 1;
    const int Lh = y2i - y1i;      // 1..127
    const int Lw = x2i - x1i;      // 1..127
    const int ylast = y2i - 1;

    const float* fp = feat + ((size_t)(b * Cc + c) * Hh) * Ww;

    // --- stage 1: per-lane column maxes; exact-trip flat row walk ---
    for (int x0 = 0; x0 < Lw; x0 += 64) {
        const int xoff = x0 + lane;
        const int xcol = x1i + min(xoff, Lw - 1);   // clamp keeps loads coalesced

        float buf[8];                               // ring, statically indexed
#pragma unroll
        for (int j = 0; j < 8; ++j)
            buf[j] = fp[(size_t)(min(y1i + j, ylast) * Ww) + xcol];

        int   p_cur = 0;
        int   e_cur = y1i + (Lh + POOL - 1) / POOL; // e(0)
        float cur   = -INFINITY;
        float prev  = -INFINITY;
        int   y     = y1i;

        const int ngroups = (Lh + 7) >> 3;
        for (int g = 0; g < ngroups; ++g) {
#pragma unroll
            for (int j = 0; j < 8; ++j) {
                const float v = buf[j];
                buf[j] = fp[(size_t)(min(y + 8, ylast) * Ww) + xcol]; // refill
                while (y >= e_cur) {                 // uniform, rarely taken
                    colmax[wave][p_cur][xoff] = cur; // flush bin
                    ++p_cur;
                    const int s_new = y1i + (p_cur * Lh) / POOL;
                    cur = (s_new == y - 1) ? prev : -INFINITY; // 1-row overlap
                    e_cur = (p_cur == POOL - 1)
                                ? 0x7fffffff         // last bin: flush in epilogue
                                : (y1i + ((p_cur + 1) * Lh + POOL - 1) / POOL);
                }
                cur  = fmaxf(cur, v);
                prev = v;
                ++y;
            }
        }
        // epilogue: flush current bin; trailing bins all start at ylast
        colmax[wave][p_cur][xoff] = cur;
        for (int p = p_cur + 1; p < POOL; ++p)
            colmax[wave][p][xoff] = prev;
    }

    __syncthreads();

    // --- stage 2: 49 lanes reduce x-bins from LDS, write 49 outputs ---
    if (lane < POOL * POOL) {
        const int p = lane / POOL;
        const int q = lane % POOL;
        const int xs = (q * Lw) / POOL;
        const int xe = ((q + 1) * Lw + POOL - 1) / POOL;
        float m = -INFINITY;
        for (int xo = xs; xo < xe; ++xo)
            m = fmaxf(m, colmax[wave][p][xo]);
        if (!valid) m = 0.0f;
        out[((size_t)bn * Cc + c) * (POOL * POOL) + lane] = m;
    }
}

extern "C" void kernel_launch(void* const* d_in, const int* in_sizes, int n_in,
                              void* d_out, int out_size, void* d_ws, size_t ws_size,
                              hipStream_t stream) {
    const float* feat  = (const float*)d_in[0];
    const float* boxes = (const float*)d_in[1];
    float* out = (float*)d_out;

    // x = channel-group (fast dim -> XCD round-robin), y = box
    dim3 grid(Cc / WAVES, Bb * Nn);   // 32 x 256 = 8192 blocks, 2 waves each
    roi_pool_kernel<<<grid, 128, 0, stream>>>(feat, boxes, out);
}